// Round 1
// baseline (1113.043 us; speedup 1.0000x reference)
//
#include <hip/hip_runtime.h>
#include <hip/hip_bf16.h>
#include <stdint.h>

// ---------- helpers ----------
__device__ __forceinline__ float tf(float v) { return v; }
__device__ __forceinline__ float tf(__hip_bfloat16 v) { return __bfloat162float(v); }

typedef __attribute__((ext_vector_type(8))) short bf16x8;
typedef __attribute__((ext_vector_type(4))) float f32x4;

#define GLD_LDS16(gp, lp)                                                        \
  __builtin_amdgcn_global_load_lds((const __attribute__((address_space(1))) void*)(gp), \
                                   (__attribute__((address_space(3))) void*)(lp), 16, 0, 0)

// ---------- tiny kernels ----------
__global__ __launch_bounds__(256) void cvt_bf16_kernel(const float* __restrict__ s,
                                                       __hip_bfloat16* __restrict__ d, int n) {
  int i = blockIdx.x * 256 + threadIdx.x;
  if (i < n) d[i] = __float2bfloat16(s[i]);
}

__global__ __launch_bounds__(256) void mask_out_kernel(const float* __restrict__ m,
                                                       float* __restrict__ o, int n) {
  int i = blockIdx.x * 256 + threadIdx.x;
  if (i < n) o[i] = (m[i] != 0.f) ? 1.f : 0.f;
}

// ---------- offset conv: off_out[b,k,t] = ob[k] + off_in[b,k,t] + sum_{c,j} ow[k,c,j]*x[b,c,t+j-1]
// grid = B * (T/64); block 256 = 4 c-groups x 64 t-lanes
template <typename XT>
__global__ __launch_bounds__(256) void offconv_kernel(const XT* __restrict__ x,
                                                      const float* __restrict__ ow,
                                                      const float* __restrict__ ob,
                                                      const float* __restrict__ offin,
                                                      float* __restrict__ offout, int T) {
  __shared__ float sw[4608];          // ow staged (3*512*3)
  __shared__ float red[3][4][64];
  int tid = threadIdx.x;
  for (int i = tid; i < 4608; i += 256) sw[i] = ow[i];
  __syncthreads();
  int lane = tid & 63, g = tid >> 6;
  int nchunk = T >> 6;
  int b = blockIdx.x / nchunk;
  int t = ((blockIdx.x % nchunk) << 6) + lane;
  const XT* xb = x + ((size_t)b * 512 + (size_t)g * 128) * T;
  float a0 = 0.f, a1 = 0.f, a2 = 0.f;
  for (int c = 0; c < 128; ++c) {
    const XT* xr = xb + (size_t)c * T;
    float xm = (t > 0) ? tf(xr[t - 1]) : 0.f;
    float x0 = tf(xr[t]);
    float xp = (t < T - 1) ? tf(xr[t + 1]) : 0.f;
    const float* wp = sw + (g * 128 + c) * 3;
    a0 += wp[0] * xm + wp[1] * x0 + wp[2] * xp;
    a1 += wp[1536] * xm + wp[1537] * x0 + wp[1538] * xp;
    a2 += wp[3072] * xm + wp[3073] * x0 + wp[3074] * xp;
  }
  red[0][g][lane] = a0;
  red[1][g][lane] = a1;
  red[2][g][lane] = a2;
  __syncthreads();
  if (g == 0) {
    for (int k = 0; k < 3; ++k) {
      float s = red[k][0][lane] + red[k][1][lane] + red[k][2][lane] + red[k][3][lane];
      int oi = (b * 3 + k) * T + t;
      offout[oi] = s + ob[k] + offin[oi];
    }
  }
}

// ---------- sampling: S[n][r] = lerp(x[b,c,p0], x[b,c,p0+1]) , r = c*3+k, n = b*T+t
template <typename XT>
__global__ __launch_bounds__(256) void sample_kernel(const XT* __restrict__ x,
                                                     const float* __restrict__ off,
                                                     __hip_bfloat16* __restrict__ S, int T,
                                                     int tsh, int total) {
  int idx = blockIdx.x * 256 + threadIdx.x;
  if (idx >= total) return;
  unsigned u = (unsigned)idx;
  unsigned n = u / 1536u;
  unsigned r = u - n * 1536u;
  unsigned c = r / 3u;
  unsigned k = r - c * 3u;
  unsigned b = n >> tsh;
  unsigned t = n & (unsigned)(T - 1);
  float o = off[((b * 3u + k) << tsh) + t];
  float pos = (float)((int)(t + k) - 1) + o;
  float p0f = floorf(pos);
  float fr = pos - p0f;
  int p0 = (int)p0f;
  const XT* xr = x + (((size_t)b * 512u + c) << tsh);
  float v0 = ((unsigned)p0 < (unsigned)T) ? tf(xr[p0]) : 0.f;
  int p1 = p0 + 1;
  float v1 = ((unsigned)p1 < (unsigned)T) ? tf(xr[p1]) : 0.f;
  S[idx] = __float2bfloat16(v0 * (1.f - fr) + v1 * fr);
}

// ---------- GEMM: C[o][n] = sum_r Wb[o][r] * S[n][r]; M=512, K=1536, N=8T
// 128x128 tile, BK=64, 256 threads (4 waves in 2x2), mfma_f32_16x16x32_bf16.
// LDS holds tiles in MFMA *fragment order*: frag f = 64 lanes x 16B, staged by
// global_load_lds (dest = base + lane*16), so ds_read_b128 at lane*16 is conflict-free.
template <bool OUT_BF16>
__global__ __launch_bounds__(256) void gemm_kernel(const __hip_bfloat16* __restrict__ Wb,
                                                   const __hip_bfloat16* __restrict__ S,
                                                   const float* __restrict__ bias,
                                                   const float* __restrict__ mask,
                                                   void* __restrict__ outp, int T, int tsh) {
  __shared__ short lds[16384];  // 16KB W-frags + 16KB S-frags
  int tid = threadIdx.x;
  int lane = tid & 63;
  int wid = tid >> 6;
  int lrow = lane & 15, lq = lane >> 4;
  int mq = wid & 1, nq = wid >> 1;
  int m0 = blockIdx.x << 7;
  int n0 = blockIdx.y << 7;

  f32x4 acc[4][4] = {};

  const __hip_bfloat16* wg0 = Wb + (size_t)(m0 + lrow) * 1536 + lq * 8;
  const __hip_bfloat16* sg0 = S + (size_t)(n0 + lrow) * 1536 + lq * 8;

  for (int kt = 0; kt < 24; ++kt) {
    int k0 = kt << 6;
    __syncthreads();
#pragma unroll
    for (int i = 0; i < 8; ++i) {
      int f = wid * 8 + i;          // 0..15: W frags, 16..31: S frags
      int kc = f & 1;
      int mt = (f >> 1) & 7;
      const __hip_bfloat16* g = (f < 16 ? wg0 : sg0) + (size_t)mt * 16 * 1536 + (k0 + kc * 32);
      GLD_LDS16(g, &lds[f * 512]);
    }
    __syncthreads();
#pragma unroll
    for (int kc = 0; kc < 2; ++kc) {
      bf16x8 av[4], bvv[4];
#pragma unroll
      for (int i = 0; i < 4; ++i)
        av[i] = *(const bf16x8*)&lds[((mq * 4 + i) * 2 + kc) * 512 + lane * 8];
#pragma unroll
      for (int j = 0; j < 4; ++j)
        bvv[j] = *(const bf16x8*)&lds[8192 + ((nq * 4 + j) * 2 + kc) * 512 + lane * 8];
#pragma unroll
      for (int i = 0; i < 4; ++i)
#pragma unroll
        for (int j = 0; j < 4; ++j)
          acc[i][j] = __builtin_amdgcn_mfma_f32_16x16x32_bf16(av[i], bvv[j], acc[i][j], 0, 0, 0);
    }
  }

  // epilogue: D row = (lane>>4)*4 + reg, col = lane&15  [verified layout]
  int bb = n0 >> tsh;
  int tb = n0 & (T - 1);
  float bvals[4][4];
#pragma unroll
  for (int i = 0; i < 4; ++i)
#pragma unroll
    for (int r = 0; r < 4; ++r) bvals[i][r] = bias[m0 + mq * 64 + i * 16 + lq * 4 + r];
#pragma unroll
  for (int j = 0; j < 4; ++j) {
    int col = nq * 64 + j * 16 + lrow;
    int t = tb + col;
    float mk = mask[(bb << tsh) + t];
#pragma unroll
    for (int i = 0; i < 4; ++i) {
      int row = mq * 64 + i * 16 + lq * 4;
#pragma unroll
      for (int r = 0; r < 4; ++r) {
        float v = acc[i][j][r] + bvals[i][r];
        v = fmaxf(v, 0.f) * mk;
        size_t oi = ((((size_t)bb << 9) + (size_t)(m0 + row + r)) << tsh) + t;
        if (OUT_BF16)
          ((__hip_bfloat16*)outp)[oi] = __float2bfloat16(v);
        else
          ((float*)outp)[oi] = v;
      }
    }
  }
}

// ---------- launch ----------
extern "C" void kernel_launch(void* const* d_in, const int* in_sizes, int n_in, void* d_out,
                              int out_size, void* d_ws, size_t ws_size, hipStream_t stream) {
  const float* feats[3] = {(const float*)d_in[0], (const float*)d_in[3], (const float*)d_in[6]};
  const float* maskp[3] = {(const float*)d_in[1], (const float*)d_in[4], (const float*)d_in[7]};
  const float* offs[3] = {(const float*)d_in[2], (const float*)d_in[5], (const float*)d_in[8]};
  const float* w[2] = {(const float*)d_in[9], (const float*)d_in[13]};
  const float* bias[2] = {(const float*)d_in[10], (const float*)d_in[14]};
  const float* ow[2] = {(const float*)d_in[11], (const float*)d_in[15]};
  const float* ob[2] = {(const float*)d_in[12], (const float*)d_in[16]};

  const int Ts[3] = {2048, 1024, 512};
  const size_t YOFF[3] = {0, 8388608, 12582912};
  const size_t MOFF[3] = {14680064, 14696448, 14704640};

  uint8_t* ws = (uint8_t*)d_ws;
  __hip_bfloat16* Wb[2] = {(__hip_bfloat16*)ws, (__hip_bfloat16*)(ws + 1572864)};
  float* offbuf = (float*)(ws + 3145728);                 // 196,608 B (level-0 size)
  __hip_bfloat16* x1 = (__hip_bfloat16*)(ws + 3342336);   // 16,777,216 B
  __hip_bfloat16* Sm = (__hip_bfloat16*)(ws + 20119552);  // 50,331,648 B

  for (int l = 0; l < 2; ++l)
    cvt_bf16_kernel<<<786432 / 256, 256, 0, stream>>>(w[l], Wb[l], 786432);

  float* outf = (float*)d_out;
  for (int lv = 0; lv < 3; ++lv) {
    int T = Ts[lv];
    int tsh = 11 - lv;
    int N = 8 * T;
    int total = N * 1536;

    mask_out_kernel<<<(8 * T + 255) / 256, 256, 0, stream>>>(maskp[lv], outf + MOFF[lv], 8 * T);

    // layer 1 (x = feats, fp32)
    offconv_kernel<float><<<8 * (T >> 6), 256, 0, stream>>>(feats[lv], ow[0], ob[0], offs[lv],
                                                            offbuf, T);
    sample_kernel<float><<<total / 256, 256, 0, stream>>>(feats[lv], offbuf, Sm, T, tsh, total);
    gemm_kernel<true><<<dim3(4, N >> 7), 256, 0, stream>>>(Wb[0], Sm, bias[0], maskp[lv],
                                                           (void*)x1, T, tsh);

    // layer 2 (x = x1, bf16)
    offconv_kernel<__hip_bfloat16><<<8 * (T >> 6), 256, 0, stream>>>(x1, ow[1], ob[1], offbuf,
                                                                     offbuf, T);
    sample_kernel<__hip_bfloat16><<<total / 256, 256, 0, stream>>>(x1, offbuf, Sm, T, tsh, total);
    gemm_kernel<false><<<dim3(4, N >> 7), 256, 0, stream>>>(Wb[1], Sm, bias[1], maskp[lv],
                                                            (void*)(outf + YOFF[lv]), T, tsh);
  }
}